// Round 2
// baseline (506.143 us; speedup 1.0000x reference)
//
#include <hip/hip_runtime.h>
#include <stdint.h>

typedef __attribute__((ext_vector_type(4))) float f32x4;
typedef __attribute__((ext_vector_type(16))) float f32x16;
typedef __attribute__((ext_vector_type(8))) short s16x8;
typedef __attribute__((ext_vector_type(4))) unsigned int u32x4;

#define D_ 1024
#define LQ 2048
#define HH_ 8
#define HD_ 128

static __device__ __forceinline__ float bf2f(ushort u){
  union { unsigned int i; float f; } v; v.i = ((unsigned int)u) << 16; return v.f;
}
static __device__ __forceinline__ ushort f2bf(float f){
  union { float f; unsigned int i; } v; v.f = f;
  unsigned int r = v.i + 0x7fffu + ((v.i >> 16) & 1u);
  return (ushort)(r >> 16);
}
static __device__ __forceinline__ unsigned int pkbf(float lo, float hi){
  unsigned int r;
  asm("v_cvt_pk_bf16_f32 %0, %1, %2" : "=v"(r) : "v"(lo), "v"(hi));
  return r;
}

// ---------------- weight fp32 -> bf16 conversion (7 matrices of 1M) --------
struct WP { const float* s[7]; };
__global__ __launch_bounds__(256) void convert_weights(WP wp, ushort* __restrict__ dst){
  int w = blockIdx.x >> 7, blk = blockIdx.x & 127, t = threadIdx.x;
  const float4* s = (const float4*)wp.s[w];
  ushort4* d = (ushort4*)(dst + (size_t)w * 1048576);
  int base = blk * 2048 + t;
  #pragma unroll
  for (int r = 0; r < 8; r++){
    float4 v = s[base + r * 256];
    ushort4 o; o.x = f2bf(v.x); o.y = f2bf(v.y); o.z = f2bf(v.z); o.w = f2bf(v.w);
    d[base + r * 256] = o;
  }
}

// ---------------- layernorm: fp32 in -> bf16 (or fp32) out ------------------
template<int OUTF>
__global__ __launch_bounds__(256) void ln_kernel(const float* __restrict__ x,
    const float* __restrict__ g, const float* __restrict__ bb,
    float* __restrict__ outf, ushort* __restrict__ outb){
  int row = blockIdx.x, t = threadIdx.x;
  const float4* xr = (const float4*)(x + (size_t)row * D_);
  float4 v = xr[t];
  float s = v.x + v.y + v.z + v.w;
  float sq = v.x*v.x + v.y*v.y + v.z*v.z + v.w*v.w;
  #pragma unroll
  for (int o = 32; o; o >>= 1){ s += __shfl_down(s, o, 64); sq += __shfl_down(sq, o, 64); }
  __shared__ float red[8];
  int lane = t & 63, wv = t >> 6;
  if (!lane){ red[wv] = s; red[wv + 4] = sq; }
  __syncthreads();
  float S = red[0] + red[1] + red[2] + red[3];
  float SQ = red[4] + red[5] + red[6] + red[7];
  float m = S * (1.f / 1024.f);
  float var = SQ * (1.f / 1024.f) - m * m;
  float inv = rsqrtf(var + 1e-8f);
  float4 gv = ((const float4*)g)[t], bv = ((const float4*)bb)[t];
  float4 y;
  y.x = (v.x - m) * inv * gv.x + bv.x;
  y.y = (v.y - m) * inv * gv.y + bv.y;
  y.z = (v.z - m) * inv * gv.z + bv.z;
  y.w = (v.w - m) * inv * gv.w + bv.w;
  if (OUTF){
    ((float4*)outf)[(size_t)row * 256 + t] = y;
  } else {
    ushort4 o4; o4.x = f2bf(y.x); o4.y = f2bf(y.y); o4.z = f2bf(y.z); o4.w = f2bf(y.w);
    ((ushort4*)outb)[(size_t)row * 256 + t] = o4;
  }
}

// ---------------- QKUV GEMM 256x128, BK=64, triple-buffered pipeline --------
// 8 waves (512 thr) as 4(M)x2(N); per-wave 64x64 output. Triple-buffered LDS
// (144 KB): iteration kt waits vmcnt(6) (own tile landed; tile kt+1 stays in
// flight), ONE s_barrier, then issues tile kt+2's 6 global_load_lds. No
// vmcnt(0) drain in the loop (T3/T4). Granule XOR swizzle: LDS slot (row,j)
// holds global k-chunk (j ^ (row&7)); frag reads are conflict-free.
// Epilogue: QKUV fused (N=4096, dst/bias by n0>>10; RoPE on Q,K) -> bf16.
struct P4 { ushort* d[4]; const float* b[4]; };

__global__ __launch_bounds__(512, 2) void gemm_qkuv(
    const ushort* __restrict__ A, const ushort* __restrict__ W, P4 io){
  __shared__ ushort As[3][256 * 64];
  __shared__ ushort Bs[3][128 * 64];
  int bid = (blockIdx.x & 7) * 64 + (blockIdx.x >> 3);   // XCD-bijective swizzle (512%8==0)
  int m0 = (bid >> 5) << 8;        // 16 m-panels of 256
  int n0g = (bid & 31) << 7;       // 32 n-panels of 128 (global N=4096)
  int t = threadIdx.x, lane = t & 63, wv = t >> 6;
  int l15 = lane & 15, quad = lane >> 4;
  int wm4 = (wv & 3) << 6;         // wave m-offset in A-tile (0..192)
  int wn2 = (wv >> 2) << 6;        // wave n-offset in B-tile (0/64)

  auto STAGE = [&](int buf, int kt){
    int k0 = kt << 6;
    #pragma unroll
    for (int r = 0; r < 4; r++){
      int g = r * 512 + (wv << 6);       // wave-uniform granule base
      int gl = g + lane;
      int row = gl >> 3;
      int kk = ((gl & 7) ^ (row & 7)) << 3;
      __builtin_amdgcn_global_load_lds(
          (const __attribute__((address_space(1))) unsigned int*)(A + (size_t)(m0 + row) * 1024 + k0 + kk),
          (__attribute__((address_space(3))) unsigned int*)&As[buf][g * 8], 16, 0, 0);
    }
    #pragma unroll
    for (int r = 0; r < 2; r++){
      int g = r * 512 + (wv << 6);
      int gl = g + lane;
      int row = gl >> 3;
      int kk = ((gl & 7) ^ (row & 7)) << 3;
      __builtin_amdgcn_global_load_lds(
          (const __attribute__((address_space(1))) unsigned int*)(W + (size_t)(n0g + row) * 1024 + k0 + kk),
          (__attribute__((address_space(3))) unsigned int*)&Bs[buf][g * 8], 16, 0, 0);
    }
  };

  f32x4 acc[4][4] = {};
  STAGE(0, 0);
  STAGE(1, 1);
  int bc = 0, bs = 2;
  for (int kt = 0; kt < 16; kt++){
    if (kt < 15) asm volatile("s_waitcnt vmcnt(6)" ::: "memory");
    else         asm volatile("s_waitcnt vmcnt(0)" ::: "memory");
    __builtin_amdgcn_s_barrier();
    asm volatile("" ::: "memory");
    __builtin_amdgcn_sched_barrier(0);
    if (kt + 2 < 16) STAGE(bs, kt + 2);
    const ushort* Ab = &As[bc][0];
    const ushort* Bb = &Bs[bc][0];
    // phase 1: all A frags + B n-tiles 0,1
    s16x8 afr[4][2];
    #pragma unroll
    for (int mi = 0; mi < 4; mi++)
      #pragma unroll
      for (int kd = 0; kd < 2; kd++){
        int R = wm4 + mi * 16 + l15;
        afr[mi][kd] = *(const s16x8*)&Ab[R * 64 + (((kd << 2) | quad) ^ (R & 7)) * 8];
      }
    s16x8 bfr[2][2];
    #pragma unroll
    for (int ni = 0; ni < 2; ni++)
      #pragma unroll
      for (int kd = 0; kd < 2; kd++){
        int R = wn2 + ni * 16 + l15;
        bfr[ni][kd] = *(const s16x8*)&Bb[R * 64 + (((kd << 2) | quad) ^ (R & 7)) * 8];
      }
    __builtin_amdgcn_s_setprio(1);
    #pragma unroll
    for (int kd = 0; kd < 2; kd++)
      #pragma unroll
      for (int mi = 0; mi < 4; mi++)
        #pragma unroll
        for (int ni = 0; ni < 2; ni++)
          acc[mi][ni] = __builtin_amdgcn_mfma_f32_16x16x32_bf16(afr[mi][kd], bfr[ni][kd], acc[mi][ni], 0, 0, 0);
    __builtin_amdgcn_s_setprio(0);
    // phase 2: B n-tiles 2,3 (A frags reused)
    s16x8 bfr2[2][2];
    #pragma unroll
    for (int ni = 0; ni < 2; ni++)
      #pragma unroll
      for (int kd = 0; kd < 2; kd++){
        int R = wn2 + (ni + 2) * 16 + l15;
        bfr2[ni][kd] = *(const s16x8*)&Bb[R * 64 + (((kd << 2) | quad) ^ (R & 7)) * 8];
      }
    __builtin_amdgcn_s_setprio(1);
    #pragma unroll
    for (int kd = 0; kd < 2; kd++)
      #pragma unroll
      for (int mi = 0; mi < 4; mi++)
        #pragma unroll
        for (int ni = 0; ni < 2; ni++)
          acc[mi][ni + 2] = __builtin_amdgcn_mfma_f32_16x16x32_bf16(afr[mi][kd], bfr2[ni][kd], acc[mi][ni + 2], 0, 0, 0);
    __builtin_amdgcn_s_setprio(0);
    bc = (bc == 2) ? 0 : bc + 1;
    bs = (bs == 2) ? 0 : bs + 1;
  }
  int sel = n0g >> 10;
  ushort* dst = io.d[sel];
  const float* bias = io.b[sel];
  int ncol = n0g & 1023;
  #pragma unroll
  for (int mi = 0; mi < 4; mi++){
    int gm = m0 + wm4 + mi * 16 + quad * 4;
    #pragma unroll
    for (int ni = 0; ni < 4; ni++){
      int cn = ncol + wn2 + ni * 16 + l15;
      float bv = bias[cn];
      if (sel < 2){
        // fused RoPE: pair (even,odd) cols live in lanes lane^1
        int i2 = (cn & 127) >> 1;
        float freq = __builtin_amdgcn_exp2f(-0.20762050f * (float)i2);  // 10000^(-2i/128)
        int odd = cn & 1;
        #pragma unroll
        for (int r = 0; r < 4; r++){
          float val = acc[mi][ni][r] + bv;
          float pv = __shfl_xor(val, 1, 64);
          int pos = (gm + r) & 2047;
          float ang = (float)pos * freq;
          float sv, cv; __sincosf(ang, &sv, &cv);
          float res = odd ? (pv * sv + val * cv) : (val * cv - pv * sv);
          dst[(size_t)(gm + r) * 1024 + cn] = f2bf(res);
        }
      } else {
        #pragma unroll
        for (int r = 0; r < 4; r++){
          float val = acc[mi][ni][r] + bv;
          dst[(size_t)(gm + r) * 1024 + cn] = f2bf(val);
        }
      }
    }
  }
}

// ---------------- GEMM 64x128 tile, BK=64, swizzled (512 blocks) ------------
// EPI: 1 = bias + residual -> fp32 ; 2 = bias + p*silu(p) -> bf16
template<int EPI>
__global__ __launch_bounds__(256, 2) void gemm_k2(
    const ushort* __restrict__ A, const ushort* __restrict__ W,
    const float* __restrict__ bias, ushort* __restrict__ dst,
    const float* __restrict__ resid, float* __restrict__ outf){
  __shared__ ushort As[64 * 64];
  __shared__ ushort Bs[128 * 64];
  int m0 = (blockIdx.x >> 3) << 6;
  int n0 = (blockIdx.x & 7) << 7;
  int t = threadIdx.x, lane = t & 63, wv = t >> 6;
  int l15 = lane & 15, quad = lane >> 4;
  int wm = (wv & 1) << 5, wn = (wv >> 1) << 6;
  f32x4 acc[2][4] = {};
  for (int k0 = 0; k0 < 1024; k0 += 64){
    #pragma unroll
    for (int r = 0; r < 6; r++){
      int cb = (r < 2 ? r * 256 : (r - 2) * 256) + wv * 64;
      int c = cb + lane;
      int row = c >> 3, j = c & 7;
      int kk = ((j ^ (row & 7)) << 3);
      if (r < 2){
        __builtin_amdgcn_global_load_lds(
            (const __attribute__((address_space(1))) unsigned int*)(A + (size_t)(m0 + row) * 1024 + k0 + kk),
            (__attribute__((address_space(3))) unsigned int*)&As[cb * 8], 16, 0, 0);
      } else {
        __builtin_amdgcn_global_load_lds(
            (const __attribute__((address_space(1))) unsigned int*)(W + (size_t)(n0 + row) * 1024 + k0 + kk),
            (__attribute__((address_space(3))) unsigned int*)&Bs[cb * 8], 16, 0, 0);
      }
    }
    __syncthreads();
    #pragma unroll
    for (int kd = 0; kd < 2; kd++){
      s16x8 afr[2], bfr[4];
      #pragma unroll
      for (int mi = 0; mi < 2; mi++){
        int R = wm + mi * 16 + l15;
        afr[mi] = *(const s16x8*)&As[R * 64 + (((kd << 2) | quad) ^ (R & 7)) * 8];
      }
      #pragma unroll
      for (int ni = 0; ni < 4; ni++){
        int R = wn + ni * 16 + l15;
        bfr[ni] = *(const s16x8*)&Bs[R * 64 + (((kd << 2) | quad) ^ (R & 7)) * 8];
      }
      #pragma unroll
      for (int mi = 0; mi < 2; mi++)
        #pragma unroll
        for (int ni = 0; ni < 4; ni++)
          acc[mi][ni] = __builtin_amdgcn_mfma_f32_16x16x32_bf16(afr[mi], bfr[ni], acc[mi][ni], 0, 0, 0);
    }
    __syncthreads();
  }
  #pragma unroll
  for (int mi = 0; mi < 2; mi++){
    int gm = m0 + wm + mi * 16 + quad * 4;
    #pragma unroll
    for (int ni = 0; ni < 4; ni++){
      int cn = n0 + wn + ni * 16 + l15;
      float bv = bias[cn];
      #pragma unroll
      for (int r = 0; r < 4; r++){
        float val = acc[mi][ni][r] + bv;
        size_t o = (size_t)(gm + r) * 1024 + cn;
        if (EPI == 1){ outf[o] = resid[o] + val; }
        else {
          float sg = __builtin_amdgcn_rcpf(1.f + __expf(-val));
          dst[o] = f2bf(val * val * sg);
        }
      }
    }
  }
}

// ---------------- V (B,L,H,HD) -> Vt (B,H,HD,sigma(L)) ----------------------
// sigma permutes keys within each 16-block (swap bits 2<->3) so that the PV
// A-fragment's natural per-lane key order (pi) matches V's column order.
__global__ __launch_bounds__(256) void transpose_v(const ushort* __restrict__ Vb, ushort* __restrict__ Vt){
  int bidx = blockIdx.x;                 // 16 bh * 32 lt * 2 dt
  int dt = bidx & 1, lt = (bidx >> 1) & 31, bh = bidx >> 6;
  int b = bh >> 3, hh = bh & 7;
  int l0 = lt << 6, d0 = dt << 6;
  __shared__ ushort tile[64][66];
  int t = threadIdx.x;
  #pragma unroll
  for (int r = 0; r < 8; r++){
    int idx = r * 256 + t;
    int row = idx >> 5, cu = idx & 31;
    unsigned int val = *(const unsigned int*)(Vb + (size_t)(b * LQ + l0 + row) * D_ + hh * HD_ + d0 + cu * 2);
    *(unsigned int*)&tile[row][cu * 2] = val;
  }
  __syncthreads();
  #pragma unroll
  for (int r = 0; r < 8; r++){
    int idx = r * 256 + t;
    int drow = idx >> 5, lu = idx & 31;
    unsigned int val = (unsigned int)tile[lu * 2][drow] | ((unsigned int)tile[lu * 2 + 1][drow] << 16);
    int kk = lu * 2;
    int x = kk & 15;
    int kkp = (kk & 48) | ((x & 4) << 1) | ((x & 8) >> 1) | (x & 3);
    *(unsigned int*)(Vt + ((size_t)(bh * HD_ + d0 + drow)) * LQ + l0 + kkp) = val;
  }
}

// ---------------- causal silu-attention, split-K, 32x32 MFMA ----------------
__global__ __launch_bounds__(256, 2) void attn_kernel(
    const ushort* __restrict__ Q, const ushort* __restrict__ K,
    const ushort* __restrict__ Vt,
    ushort* __restrict__ Po0, ushort* __restrict__ Po1){
  __shared__ ushort Ks[2][64 * 128];
  __shared__ ushort Vs[2][128 * 64];
  int t = threadIdx.x, lane = t & 63, wv = t >> 6;
  int l31 = lane & 31, h = lane >> 5;
  int idx = blockIdx.x;
  int bh = idx & 15;
  int s = idx >> 4;
  int qt = (s < 16) ? (15 - (s >> 1)) : ((s - 16) >> 1);
  int half = s & 1;
  int ntiles = 2 * qt + 2;
  int c0 = qt + 1;
  int klo = half ? c0 : 0;
  int khi = half ? ntiles : c0;
  if (klo >= khi) return;
  int b = bh >> 3, hh = bh & 7;
  int q0 = qt << 7;
  const float scale = 0.08838834764831845f;  // 1/sqrt(128)

  // Q fragments (B-operand): col = q = lane&31, k(hd) = 16*kd + 8*h + j
  s16x8 qf[8];
  const ushort* qbase = Q + (size_t)(b * LQ + q0 + (wv << 5) + l31) * D_ + hh * HD_;
  #pragma unroll
  for (int kd = 0; kd < 8; kd++) qf[kd] = *(const s16x8*)(qbase + kd * 16 + h * 8);

  auto STAGE = [&](int p, int kt){
    int k0 = kt << 6;
    #pragma unroll
    for (int r = 0; r < 4; r++){
      int cb = r * 256 + (wv << 6);    // wave-uniform slot base
      int c = cb + lane;               // 16B slot id 0..1023
      int R = c >> 4, sl = c & 15;
      int gg = sl ^ (R & 7);           // swizzled source granule
      __builtin_amdgcn_global_load_lds(
          (const __attribute__((address_space(1))) unsigned int*)(K + (size_t)(b * LQ + k0 + R) * D_ + hh * HD_ + gg * 8),
          (__attribute__((address_space(3))) unsigned int*)&Ks[p][cb * 8], 16, 0, 0);
    }
    #pragma unroll
    for (int r = 0; r < 4; r++){
      int cb = r * 256 + (wv << 6);
      int c = cb + lane;
      int R = c >> 3, sl = c & 7;
      int gg = sl ^ (R & 7);
      __builtin_amdgcn_global_load_lds(
          (const __attribute__((address_space(1))) unsigned int*)(Vt + (size_t)(bh * HD_ + R) * LQ + k0 + gg * 8),
          (__attribute__((address_space(3))) unsigned int*)&Vs[p][cb * 8], 16, 0, 0);
    }
  };

  f32x16 acc_o[4] = {};
  int qg = q0 + (wv << 5) + l31;

  STAGE(0, klo);
  __syncthreads();
  for (int kt = klo; kt < khi; kt++){
    int p = (kt - klo) & 1;
    if (kt + 1 < khi) STAGE(p ^ 1, kt + 1);
    // swapped QK^T: S^T[key][q], col = q = lane&31
    f32x16 sacc[2] = {};
    #pragma unroll
    for (int kd = 0; kd < 8; kd++){
      #pragma unroll
      for (int kb = 0; kb < 2; kb++){
        int R = (kb << 5) + l31;
        s16x8 af = *(const s16x8*)&Ks[p][(R * 16 + (((kd << 1) | h) ^ (R & 7))) * 8];
        sacc[kb] = __builtin_amdgcn_mfma_f32_32x32x16_bf16(af, qf[kd], sacc[kb], 0, 0, 0);
      }
    }
    // silu + causal mask + in-register pack to PV A-fragments
    int k0 = kt << 6;
    s16x8 pf[4];
    #pragma unroll
    for (int kb = 0; kb < 2; kb++){
      float pvv[16];
      #pragma unroll
      for (int r = 0; r < 16; r++){
        int kg = k0 + (kb << 5) + (r & 3) + ((r >> 2) << 3) + (h << 2);
        float sv = sacc[kb][r] * scale;
        float pp = sv * __builtin_amdgcn_rcpf(1.f + __expf(-sv));
        pvv[r] = (kg <= qg) ? pp : 0.f;
      }
      #pragma unroll
      for (int cc = 0; cc < 2; cc++){
        union { u32x4 u; s16x8 v; } w;
        w.u[0] = pkbf(pvv[cc*8+0], pvv[cc*8+1]);
        w.u[1] = pkbf(pvv[cc*8+2], pvv[cc*8+3]);
        w.u[2] = pkbf(pvv[cc*8+4], pvv[cc*8+5]);
        w.u[3] = pkbf(pvv[cc*8+6], pvv[cc*8+7]);
        pf[(kb << 1) | cc] = w.v;
      }
    }
    // PV: O[q][d] += P * V  (V columns sigma-permuted to match pf key order)
    #pragma unroll
    for (int kv = 0; kv < 4; kv++){
      #pragma unroll
      for (int nt = 0; nt < 4; nt++){
        int R = (nt << 5) + l31;
        s16x8 vf = *(const s16x8*)&Vs[p][(R * 8 + (((kv << 1) | h) ^ (R & 7))) * 8];
        acc_o[nt] = __builtin_amdgcn_mfma_f32_32x32x16_bf16(pf[kv], vf, acc_o[nt], 0, 0, 0);
      }
    }
    __syncthreads();
  }
  ushort* Po = half ? Po1 : Po0;
  #pragma unroll
  for (int nt = 0; nt < 4; nt++){
    #pragma unroll
    for (int r = 0; r < 16; r++){
      int qq = q0 + (wv << 5) + (r & 3) + ((r >> 2) << 3) + (h << 2);
      int dd = (nt << 5) + l31;
      Po[(size_t)(b * LQ + qq) * D_ + hh * HD_ + dd] = f2bf(acc_o[nt][r]);
    }
  }
}

// ---------------- attn partial reduce: (P0 + P1) * U -> bf16 ----------------
__global__ __launch_bounds__(256) void attn_reduce(
    const ushort* __restrict__ Po0, const ushort* __restrict__ Po1,
    const ushort* __restrict__ U, ushort* __restrict__ Aout){
  int i = (blockIdx.x * 256 + threadIdx.x) * 4;   // 4M elems total
  ushort4 p0 = *(const ushort4*)(Po0 + i);
  ushort4 p1 = *(const ushort4*)(Po1 + i);
  float v0 = bf2f(p0.x) + bf2f(p1.x);
  float v1 = bf2f(p0.y) + bf2f(p1.y);
  float v2 = bf2f(p0.z) + bf2f(p1.z);
  float v3 = bf2f(p0.w) + bf2f(p1.w);
  ushort4 u = *(const ushort4*)(U + i);
  ushort4 o;
  o.x = f2bf(v0 * bf2f(u.x)); o.y = f2bf(v1 * bf2f(u.y));
  o.z = f2bf(v2 * bf2f(u.z)); o.w = f2bf(v3 * bf2f(u.w));
  *(ushort4*)(Aout + i) = o;
}

// ---------------- launcher --------------------------------------------------
extern "C" void kernel_launch(void* const* d_in, const int* in_sizes, int n_in,
                              void* d_out, int out_size, void* d_ws, size_t ws_size,
                              hipStream_t stream){
  const float* seqs = (const float*)d_in[0];
  const float* bq = (const float*)d_in[3];
  const float* bk = (const float*)d_in[5];
  const float* bu = (const float*)d_in[7];
  const float* bv = (const float*)d_in[9];
  const float* bo = (const float*)d_in[11];
  const float* b1 = (const float*)d_in[13];
  const float* b2 = (const float*)d_in[15];
  const float* ln1g = (const float*)d_in[16];
  const float* ln1b = (const float*)d_in[17];
  const float* ln2g = (const float*)d_in[18];
  const float* ln2b = (const float*)d_in[19];
  const float* lnfg = (const float*)d_in[20];
  const float* lnfb = (const float*)d_in[21];

  char* base = (char*)d_ws;
  const size_t MB = 1u << 20;
  if (ws_size < 78 * MB) return;  // defensive
  ushort* wbf = (ushort*)base;                   // 14 MB
  ushort* h   = (ushort*)(base + 14 * MB);       // 8 MB (ln out; attn Po0; attn out)
  ushort* Qb  = (ushort*)(base + 22 * MB);       // 8 MB (also MLP hidden)
  ushort* Kb  = (ushort*)(base + 30 * MB);       // 8 MB
  ushort* Ub  = (ushort*)(base + 38 * MB);       // 8 MB
  ushort* Vb  = (ushort*)(base + 46 * MB);       // 8 MB (attn Po1 after transpose)
  ushort* Vt  = (ushort*)(base + 54 * MB);       // 8 MB
  float*  xb  = (float*)(base + 62 * MB);        // 16 MB
  ushort* ab  = h;

  const size_t DD = 1048576;
  for (int i = 0; i < 2; i++){
    WP wp;
    for (int j = 0; j < 7; j++)
      wp.s[j] = (const float*)d_in[2 + 2 * j] + (size_t)i * DD;
    convert_weights<<<7 * 128, 256, 0, stream>>>(wp, wbf);
    const ushort* Wl = wbf;
    const float* xin = (i == 0) ? seqs : xb;
    ln_kernel<0><<<4096, 256, 0, stream>>>(xin, ln1g + i * D_, ln1b + i * D_, nullptr, h);
    // fused QKUV projection (N=4096) with fused RoPE on Q,K
    P4 io_qkuv = {{Qb, Kb, Ub, Vb}, {bq + i * D_, bk + i * D_, bu + i * D_, bv + i * D_}};
    gemm_qkuv<<<512, 512, 0, stream>>>(h, Wl, io_qkuv);
    transpose_v<<<1024, 256, 0, stream>>>(Vb, Vt);
    attn_kernel<<<512, 256, 0, stream>>>(Qb, Kb, Vt, ab, Vb);
    attn_reduce<<<4096, 256, 0, stream>>>(ab, Vb, Ub, ab);
    gemm_k2<1><<<512, 256, 0, stream>>>(ab, Wl + 4 * DD, bo + i * D_, nullptr, xin, xb);
    ln_kernel<0><<<4096, 256, 0, stream>>>(xb, ln2g + i * D_, ln2b + i * D_, nullptr, h);
    gemm_k2<2><<<512, 256, 0, stream>>>(h, Wl + 5 * DD, b1 + i * D_, Qb, nullptr, nullptr);
    gemm_k2<1><<<512, 256, 0, stream>>>(Qb, Wl + 6 * DD, b2 + i * D_, nullptr, xb, xb);
  }
  ln_kernel<1><<<4096, 256, 0, stream>>>(xb, lnfg, lnfb, (float*)d_out, nullptr);
}

// Round 3
// 487.218 us; speedup vs baseline: 1.0388x; 1.0388x over previous
//
#include <hip/hip_runtime.h>
#include <stdint.h>

typedef __attribute__((ext_vector_type(4))) float f32x4;
typedef __attribute__((ext_vector_type(16))) float f32x16;
typedef __attribute__((ext_vector_type(8))) short s16x8;
typedef __attribute__((ext_vector_type(4))) unsigned int u32x4;

#define D_ 1024
#define LQ 2048
#define HH_ 8
#define HD_ 128

static __device__ __forceinline__ float bf2f(ushort u){
  union { unsigned int i; float f; } v; v.i = ((unsigned int)u) << 16; return v.f;
}
static __device__ __forceinline__ ushort f2bf(float f){
  union { float f; unsigned int i; } v; v.f = f;
  unsigned int r = v.i + 0x7fffu + ((v.i >> 16) & 1u);
  return (ushort)(r >> 16);
}
static __device__ __forceinline__ unsigned int pkbf(float lo, float hi){
  unsigned int r;
  asm("v_cvt_pk_bf16_f32 %0, %1, %2" : "=v"(r) : "v"(lo), "v"(hi));
  return r;
}

// ---------------- weight fp32 -> bf16 conversion (7 matrices of 1M) --------
struct WP { const float* s[7]; };
__global__ __launch_bounds__(256) void convert_weights(WP wp, ushort* __restrict__ dst){
  int w = blockIdx.x >> 7, blk = blockIdx.x & 127, t = threadIdx.x;
  const float4* s = (const float4*)wp.s[w];
  ushort4* d = (ushort4*)(dst + (size_t)w * 1048576);
  int base = blk * 2048 + t;
  #pragma unroll
  for (int r = 0; r < 8; r++){
    float4 v = s[base + r * 256];
    ushort4 o; o.x = f2bf(v.x); o.y = f2bf(v.y); o.z = f2bf(v.z); o.w = f2bf(v.w);
    d[base + r * 256] = o;
  }
}

// ---------------- layernorm: fp32 in -> bf16 (or fp32) out ------------------
template<int OUTF>
__global__ __launch_bounds__(256) void ln_kernel(const float* __restrict__ x,
    const float* __restrict__ g, const float* __restrict__ bb,
    float* __restrict__ outf, ushort* __restrict__ outb){
  int row = blockIdx.x, t = threadIdx.x;
  const float4* xr = (const float4*)(x + (size_t)row * D_);
  float4 v = xr[t];
  float s = v.x + v.y + v.z + v.w;
  float sq = v.x*v.x + v.y*v.y + v.z*v.z + v.w*v.w;
  #pragma unroll
  for (int o = 32; o; o >>= 1){ s += __shfl_down(s, o, 64); sq += __shfl_down(sq, o, 64); }
  __shared__ float red[8];
  int lane = t & 63, wv = t >> 6;
  if (!lane){ red[wv] = s; red[wv + 4] = sq; }
  __syncthreads();
  float S = red[0] + red[1] + red[2] + red[3];
  float SQ = red[4] + red[5] + red[6] + red[7];
  float m = S * (1.f / 1024.f);
  float var = SQ * (1.f / 1024.f) - m * m;
  float inv = rsqrtf(var + 1e-8f);
  float4 gv = ((const float4*)g)[t], bv = ((const float4*)bb)[t];
  float4 y;
  y.x = (v.x - m) * inv * gv.x + bv.x;
  y.y = (v.y - m) * inv * gv.y + bv.y;
  y.z = (v.z - m) * inv * gv.z + bv.z;
  y.w = (v.w - m) * inv * gv.w + bv.w;
  if (OUTF){
    ((float4*)outf)[(size_t)row * 256 + t] = y;
  } else {
    ushort4 o4; o4.x = f2bf(y.x); o4.y = f2bf(y.y); o4.z = f2bf(y.z); o4.w = f2bf(y.w);
    ((ushort4*)outb)[(size_t)row * 256 + t] = o4;
  }
}

// ---------------- QKUV GEMM: 256x256 tile, BK=64, 8-phase schedule ----------
// m201 template port: 8 waves (2M x 4N), per-wave 128x64 out, LDS 128 KB =
// 2 buf x 2 half x 128x64 bf16 x {A,B}. Per iteration: 2 K-tiles, 8 phases:
// {ds_read quadrant frags | stage 1 half-tile | [vmcnt@ph4/8] | barrier |
//  lgkmcnt(0) | setprio(1) 16 MFMA setprio(0) | barrier}. vmcnt(6) counted,
// never 0 in steady state (3 half-tiles in flight). Granule XOR swizzle:
// LDS slot (row,j) holds global k-chunk j^(row&7); linear dest for
// global_load_lds, swizzled source + swizzled ds_read. Grid 256 = 1/CU,
// XCD chunking 4m x 8n. Epilogue: QKUV fused, RoPE on Q,K -> bf16.
struct P4 { ushort* d[4]; const float* b[4]; };

__global__ __launch_bounds__(512, 2) void gemm_qkuv(
    const ushort* __restrict__ A, const ushort* __restrict__ W, P4 io){
  __shared__ ushort As[2][2][128 * 64];
  __shared__ ushort Bs[2][2][128 * 64];
  int xcd = blockIdx.x & 7, slot = blockIdx.x >> 3;
  int mip = (xcd >> 1) * 4 + (slot >> 3);   // 0..15
  int nip = (xcd & 1) * 8 + (slot & 7);     // 0..15
  int m0 = mip << 8, n0 = nip << 8;
  int t = threadIdx.x, lane = t & 63, wv = t >> 6;
  int l15 = lane & 15, quad = lane >> 4;
  int wm = wv >> 2;            // 0..1  (A-half = wm)
  int wn = wv & 3;             // 0..3
  int bh = wn >> 1;            // B-half
  int bcol = (wn & 1) << 6;    // row offset within B-half

  const ushort* Ab0 = &As[0][wm][0];
  const ushort* Ab1 = &As[1][wm][0];
  const ushort* Bb0 = &Bs[0][bh][0];
  const ushort* Bb1 = &Bs[1][bh][0];

  auto stA = [&](int buf, int half, int kt){
    #pragma unroll
    for (int i = 0; i < 2; i++){
      int gb = i * 512 + (wv << 6);
      int g = gb + lane;
      int row = g >> 3;
      int kk = ((g & 7) ^ (row & 7)) << 3;
      __builtin_amdgcn_global_load_lds(
          (const __attribute__((address_space(1))) unsigned int*)(A + (size_t)(m0 + half * 128 + row) * 1024 + kt * 64 + kk),
          (__attribute__((address_space(3))) unsigned int*)&As[buf][half][gb * 8], 16, 0, 0);
    }
  };
  auto stB = [&](int buf, int half, int kt){
    #pragma unroll
    for (int i = 0; i < 2; i++){
      int gb = i * 512 + (wv << 6);
      int g = gb + lane;
      int row = g >> 3;
      int kk = ((g & 7) ^ (row & 7)) << 3;
      __builtin_amdgcn_global_load_lds(
          (const __attribute__((address_space(1))) unsigned int*)(W + (size_t)(n0 + half * 128 + row) * 1024 + kt * 64 + kk),
          (__attribute__((address_space(3))) unsigned int*)&Bs[buf][half][gb * 8], 16, 0, 0);
    }
  };

  f32x4 acc[8][4] = {};
  s16x8 afr[4][2], bfrL[2][2], bfrH[2][2];

  auto dsA = [&](const ushort* base, int mq){
    #pragma unroll
    for (int mi = 0; mi < 4; mi++)
      #pragma unroll
      for (int kd = 0; kd < 2; kd++){
        int R = mq * 64 + mi * 16 + l15;
        afr[mi][kd] = *(const s16x8*)&base[R * 64 + (((kd << 2) | quad) ^ (R & 7)) * 8];
      }
  };
  auto dsBL = [&](const ushort* base){
    #pragma unroll
    for (int ni = 0; ni < 2; ni++)
      #pragma unroll
      for (int kd = 0; kd < 2; kd++){
        int r = bcol + ni * 16 + l15;
        bfrL[ni][kd] = *(const s16x8*)&base[r * 64 + (((kd << 2) | quad) ^ (r & 7)) * 8];
      }
  };
  auto dsBH = [&](const ushort* base){
    #pragma unroll
    for (int ni = 0; ni < 2; ni++)
      #pragma unroll
      for (int kd = 0; kd < 2; kd++){
        int r = bcol + 32 + ni * 16 + l15;
        bfrH[ni][kd] = *(const s16x8*)&base[r * 64 + (((kd << 2) | quad) ^ (r & 7)) * 8];
      }
  };
  auto MM = [&](int mq, int nq, s16x8 (&bf)[2][2]){
    __builtin_amdgcn_s_setprio(1);
    #pragma unroll
    for (int kd = 0; kd < 2; kd++)
      #pragma unroll
      for (int mi = 0; mi < 4; mi++)
        #pragma unroll
        for (int ni = 0; ni < 2; ni++)
          acc[mq * 4 + mi][nq * 2 + ni] = __builtin_amdgcn_mfma_f32_16x16x32_bf16(
              afr[mi][kd], bf[ni][kd], acc[mq * 4 + mi][nq * 2 + ni], 0, 0, 0);
    __builtin_amdgcn_s_setprio(0);
  };

  // prologue: buf0 full (K-tile 0), buf1 minus A-half1 (K-tile 1)
  stA(0, 0, 0); stA(0, 1, 0); stB(0, 0, 0); stB(0, 1, 0);
  stB(1, 0, 1); stB(1, 1, 1); stA(1, 0, 1);
  asm volatile("s_waitcnt vmcnt(6)" ::: "memory");
  __builtin_amdgcn_s_barrier();

  for (int it = 0; it < 8; ++it){
    int kt1 = 2 * it + 1, kt2 = 2 * it + 2, kt3 = 2 * it + 3;
    bool g1 = (it < 7);
    // ph1: Q(0,0) buf0
    dsA(Ab0, 0); dsBL(Bb0);
    stA(1, 1, kt1);
    __builtin_amdgcn_s_barrier();
    asm volatile("s_waitcnt lgkmcnt(0)" ::: "memory");
    MM(0, 0, bfrL);
    __builtin_amdgcn_s_barrier();
    // ph2: Q(0,1) buf0
    dsBH(Bb0);
    __builtin_amdgcn_s_barrier();
    asm volatile("s_waitcnt lgkmcnt(0)" ::: "memory");
    MM(0, 1, bfrH);
    __builtin_amdgcn_s_barrier();
    // ph3: Q(1,0) buf0
    dsA(Ab0, 1);
    if (g1) stB(0, 0, kt2);
    __builtin_amdgcn_s_barrier();
    asm volatile("s_waitcnt lgkmcnt(0)" ::: "memory");
    MM(1, 0, bfrL);
    __builtin_amdgcn_s_barrier();
    // ph4: Q(1,1) buf0  [certify buf1]
    if (g1){ stB(0, 1, kt2); stA(0, 0, kt2); }
    if (g1) asm volatile("s_waitcnt vmcnt(6)" ::: "memory");
    else    asm volatile("s_waitcnt vmcnt(0)" ::: "memory");
    __builtin_amdgcn_s_barrier();
    MM(1, 1, bfrH);
    __builtin_amdgcn_s_barrier();
    // ph5: Q(0,0) buf1
    dsA(Ab1, 0); dsBL(Bb1);
    if (g1) stA(0, 1, kt2);
    __builtin_amdgcn_s_barrier();
    asm volatile("s_waitcnt lgkmcnt(0)" ::: "memory");
    MM(0, 0, bfrL);
    __builtin_amdgcn_s_barrier();
    // ph6: Q(0,1) buf1
    dsBH(Bb1);
    __builtin_amdgcn_s_barrier();
    asm volatile("s_waitcnt lgkmcnt(0)" ::: "memory");
    MM(0, 1, bfrH);
    __builtin_amdgcn_s_barrier();
    // ph7: Q(1,0) buf1
    dsA(Ab1, 1);
    if (g1) stB(1, 0, kt3);
    __builtin_amdgcn_s_barrier();
    asm volatile("s_waitcnt lgkmcnt(0)" ::: "memory");
    MM(1, 0, bfrL);
    __builtin_amdgcn_s_barrier();
    // ph8: Q(1,1) buf1  [certify buf0 of next iter]
    if (g1){ stB(1, 1, kt3); stA(1, 0, kt3); }
    if (g1) asm volatile("s_waitcnt vmcnt(6)" ::: "memory");
    __builtin_amdgcn_s_barrier();
    MM(1, 1, bfrH);
    __builtin_amdgcn_s_barrier();
  }

  // epilogue: QKUV select + bias (+ RoPE on Q,K)
  #pragma unroll
  for (int ni4 = 0; ni4 < 4; ni4++){
    int cng = n0 + (wn << 6) + ni4 * 16 + l15;
    int sel = cng >> 10;
    ushort* dst = io.d[sel];
    float bv = io.b[sel][cng & 1023];
    int cn = cng & 1023;
    if (sel < 2){
      int i2 = (cn & 127) >> 1;
      float freq = __builtin_amdgcn_exp2f(-0.20762050f * (float)i2);  // 10000^(-2i/128)
      int odd = cn & 1;
      #pragma unroll
      for (int mi8 = 0; mi8 < 8; mi8++){
        int gm = m0 + (wm << 7) + mi8 * 16 + quad * 4;
        #pragma unroll
        for (int r = 0; r < 4; r++){
          float val = acc[mi8][ni4][r] + bv;
          float pv = __shfl_xor(val, 1, 64);
          int pos = (gm + r) & 2047;
          float ang = (float)pos * freq;
          float sv, cv; __sincosf(ang, &sv, &cv);
          float res = odd ? (pv * sv + val * cv) : (val * cv - pv * sv);
          dst[(size_t)(gm + r) * 1024 + cn] = f2bf(res);
        }
      }
    } else {
      #pragma unroll
      for (int mi8 = 0; mi8 < 8; mi8++){
        int gm = m0 + (wm << 7) + mi8 * 16 + quad * 4;
        #pragma unroll
        for (int r = 0; r < 4; r++){
          float val = acc[mi8][ni4][r] + bv;
          dst[(size_t)(gm + r) * 1024 + cn] = f2bf(val);
        }
      }
    }
  }
}

// ---------------- GEMM 64x128 tile, BK=64, swizzled (512 blocks) ------------
// EPI: 1 = bias + residual -> fp32 ; 2 = bias + p*silu(p) -> bf16
template<int EPI>
__global__ __launch_bounds__(256, 2) void gemm_k2(
    const ushort* __restrict__ A, const ushort* __restrict__ W,
    const float* __restrict__ bias, ushort* __restrict__ dst,
    const float* __restrict__ resid, float* __restrict__ outf){
  __shared__ ushort As[64 * 64];
  __shared__ ushort Bs[128 * 64];
  int m0 = (blockIdx.x >> 3) << 6;
  int n0 = (blockIdx.x & 7) << 7;
  int t = threadIdx.x, lane = t & 63, wv = t >> 6;
  int l15 = lane & 15, quad = lane >> 4;
  int wm = (wv & 1) << 5, wn = (wv >> 1) << 6;
  f32x4 acc[2][4] = {};
  for (int k0 = 0; k0 < 1024; k0 += 64){
    #pragma unroll
    for (int r = 0; r < 6; r++){
      int cb = (r < 2 ? r * 256 : (r - 2) * 256) + wv * 64;
      int c = cb + lane;
      int row = c >> 3, j = c & 7;
      int kk = ((j ^ (row & 7)) << 3);
      if (r < 2){
        __builtin_amdgcn_global_load_lds(
            (const __attribute__((address_space(1))) unsigned int*)(A + (size_t)(m0 + row) * 1024 + k0 + kk),
            (__attribute__((address_space(3))) unsigned int*)&As[cb * 8], 16, 0, 0);
      } else {
        __builtin_amdgcn_global_load_lds(
            (const __attribute__((address_space(1))) unsigned int*)(W + (size_t)(n0 + row) * 1024 + k0 + kk),
            (__attribute__((address_space(3))) unsigned int*)&Bs[cb * 8], 16, 0, 0);
      }
    }
    __syncthreads();
    #pragma unroll
    for (int kd = 0; kd < 2; kd++){
      s16x8 afr[2], bfr[4];
      #pragma unroll
      for (int mi = 0; mi < 2; mi++){
        int R = wm + mi * 16 + l15;
        afr[mi] = *(const s16x8*)&As[R * 64 + (((kd << 2) | quad) ^ (R & 7)) * 8];
      }
      #pragma unroll
      for (int ni = 0; ni < 4; ni++){
        int R = wn + ni * 16 + l15;
        bfr[ni] = *(const s16x8*)&Bs[R * 64 + (((kd << 2) | quad) ^ (R & 7)) * 8];
      }
      #pragma unroll
      for (int mi = 0; mi < 2; mi++)
        #pragma unroll
        for (int ni = 0; ni < 4; ni++)
          acc[mi][ni] = __builtin_amdgcn_mfma_f32_16x16x32_bf16(afr[mi], bfr[ni], acc[mi][ni], 0, 0, 0);
    }
    __syncthreads();
  }
  #pragma unroll
  for (int mi = 0; mi < 2; mi++){
    int gm = m0 + wm + mi * 16 + quad * 4;
    #pragma unroll
    for (int ni = 0; ni < 4; ni++){
      int cn = n0 + wn + ni * 16 + l15;
      float bv = bias[cn];
      #pragma unroll
      for (int r = 0; r < 4; r++){
        float val = acc[mi][ni][r] + bv;
        size_t o = (size_t)(gm + r) * 1024 + cn;
        if (EPI == 1){ outf[o] = resid[o] + val; }
        else {
          float sg = __builtin_amdgcn_rcpf(1.f + __expf(-val));
          dst[o] = f2bf(val * val * sg);
        }
      }
    }
  }
}

// ---------------- V (B,L,H,HD) -> Vt (B,H,HD,sigma(L)) ----------------------
__global__ __launch_bounds__(256) void transpose_v(const ushort* __restrict__ Vb, ushort* __restrict__ Vt){
  int bidx = blockIdx.x;                 // 16 bh * 32 lt * 2 dt
  int dt = bidx & 1, lt = (bidx >> 1) & 31, bh = bidx >> 6;
  int b = bh >> 3, hh = bh & 7;
  int l0 = lt << 6, d0 = dt << 6;
  __shared__ ushort tile[64][66];
  int t = threadIdx.x;
  #pragma unroll
  for (int r = 0; r < 8; r++){
    int idx = r * 256 + t;
    int row = idx >> 5, cu = idx & 31;
    unsigned int val = *(const unsigned int*)(Vb + (size_t)(b * LQ + l0 + row) * D_ + hh * HD_ + d0 + cu * 2);
    *(unsigned int*)&tile[row][cu * 2] = val;
  }
  __syncthreads();
  #pragma unroll
  for (int r = 0; r < 8; r++){
    int idx = r * 256 + t;
    int drow = idx >> 5, lu = idx & 31;
    unsigned int val = (unsigned int)tile[lu * 2][drow] | ((unsigned int)tile[lu * 2 + 1][drow] << 16);
    int kk = lu * 2;
    int x = kk & 15;
    int kkp = (kk & 48) | ((x & 4) << 1) | ((x & 8) >> 1) | (x & 3);
    *(unsigned int*)(Vt + ((size_t)(bh * HD_ + d0 + drow)) * LQ + l0 + kkp) = val;
  }
}

// ---------------- causal silu-attention, split-K, 32x32 MFMA ----------------
__global__ __launch_bounds__(256, 2) void attn_kernel(
    const ushort* __restrict__ Q, const ushort* __restrict__ K,
    const ushort* __restrict__ Vt,
    ushort* __restrict__ Po0, ushort* __restrict__ Po1){
  __shared__ ushort Ks[2][64 * 128];
  __shared__ ushort Vs[2][128 * 64];
  int t = threadIdx.x, lane = t & 63, wv = t >> 6;
  int l31 = lane & 31, h = lane >> 5;
  int idx = blockIdx.x;
  int bh = idx & 15;
  int s = idx >> 4;
  int qt = (s < 16) ? (15 - (s >> 1)) : ((s - 16) >> 1);
  int half = s & 1;
  int ntiles = 2 * qt + 2;
  int c0 = qt + 1;
  int klo = half ? c0 : 0;
  int khi = half ? ntiles : c0;
  if (klo >= khi) return;
  int b = bh >> 3, hh = bh & 7;
  int q0 = qt << 7;
  const float scale = 0.08838834764831845f;  // 1/sqrt(128)

  // Q fragments (B-operand): col = q = lane&31, k(hd) = 16*kd + 8*h + j
  s16x8 qf[8];
  const ushort* qbase = Q + (size_t)(b * LQ + q0 + (wv << 5) + l31) * D_ + hh * HD_;
  #pragma unroll
  for (int kd = 0; kd < 8; kd++) qf[kd] = *(const s16x8*)(qbase + kd * 16 + h * 8);

  auto STAGE = [&](int p, int kt){
    int k0 = kt << 6;
    #pragma unroll
    for (int r = 0; r < 4; r++){
      int cb = r * 256 + (wv << 6);    // wave-uniform slot base
      int c = cb + lane;               // 16B slot id 0..1023
      int R = c >> 4, sl = c & 15;
      int gg = sl ^ (R & 7);           // swizzled source granule
      __builtin_amdgcn_global_load_lds(
          (const __attribute__((address_space(1))) unsigned int*)(K + (size_t)(b * LQ + k0 + R) * D_ + hh * HD_ + gg * 8),
          (__attribute__((address_space(3))) unsigned int*)&Ks[p][cb * 8], 16, 0, 0);
    }
    #pragma unroll
    for (int r = 0; r < 4; r++){
      int cb = r * 256 + (wv << 6);
      int c = cb + lane;
      int R = c >> 3, sl = c & 7;
      int gg = sl ^ (R & 7);
      __builtin_amdgcn_global_load_lds(
          (const __attribute__((address_space(1))) unsigned int*)(Vt + (size_t)(bh * HD_ + R) * LQ + k0 + gg * 8),
          (__attribute__((address_space(3))) unsigned int*)&Vs[p][cb * 8], 16, 0, 0);
    }
  };

  f32x16 acc_o[4] = {};
  int qg = q0 + (wv << 5) + l31;

  STAGE(0, klo);
  __syncthreads();
  for (int kt = klo; kt < khi; kt++){
    int p = (kt - klo) & 1;
    if (kt + 1 < khi) STAGE(p ^ 1, kt + 1);
    // swapped QK^T: S^T[key][q], col = q = lane&31
    f32x16 sacc[2] = {};
    #pragma unroll
    for (int kd = 0; kd < 8; kd++){
      #pragma unroll
      for (int kb = 0; kb < 2; kb++){
        int R = (kb << 5) + l31;
        s16x8 af = *(const s16x8*)&Ks[p][(R * 16 + (((kd << 1) | h) ^ (R & 7))) * 8];
        sacc[kb] = __builtin_amdgcn_mfma_f32_32x32x16_bf16(af, qf[kd], sacc[kb], 0, 0, 0);
      }
    }
    // silu + causal mask + in-register pack to PV A-fragments
    int k0 = kt << 6;
    s16x8 pf[4];
    #pragma unroll
    for (int kb = 0; kb < 2; kb++){
      float pvv[16];
      #pragma unroll
      for (int r = 0; r < 16; r++){
        int kg = k0 + (kb << 5) + (r & 3) + ((r >> 2) << 3) + (h << 2);
        float sv = sacc[kb][r] * scale;
        float pp = sv * __builtin_amdgcn_rcpf(1.f + __expf(-sv));
        pvv[r] = (kg <= qg) ? pp : 0.f;
      }
      #pragma unroll
      for (int cc = 0; cc < 2; cc++){
        union { u32x4 u; s16x8 v; } w;
        w.u[0] = pkbf(pvv[cc*8+0], pvv[cc*8+1]);
        w.u[1] = pkbf(pvv[cc*8+2], pvv[cc*8+3]);
        w.u[2] = pkbf(pvv[cc*8+4], pvv[cc*8+5]);
        w.u[3] = pkbf(pvv[cc*8+6], pvv[cc*8+7]);
        pf[(kb << 1) | cc] = w.v;
      }
    }
    // PV: O[q][d] += P * V  (V columns sigma-permuted to match pf key order)
    #pragma unroll
    for (int kv = 0; kv < 4; kv++){
      #pragma unroll
      for (int nt = 0; nt < 4; nt++){
        int R = (nt << 5) + l31;
        s16x8 vf = *(const s16x8*)&Vs[p][(R * 8 + (((kv << 1) | h) ^ (R & 7))) * 8];
        acc_o[nt] = __builtin_amdgcn_mfma_f32_32x32x16_bf16(pf[kv], vf, acc_o[nt], 0, 0, 0);
      }
    }
    __syncthreads();
  }
  ushort* Po = half ? Po1 : Po0;
  #pragma unroll
  for (int nt = 0; nt < 4; nt++){
    #pragma unroll
    for (int r = 0; r < 16; r++){
      int qq = q0 + (wv << 5) + (r & 3) + ((r >> 2) << 3) + (h << 2);
      int dd = (nt << 5) + l31;
      Po[(size_t)(b * LQ + qq) * D_ + hh * HD_ + dd] = f2bf(acc_o[nt][r]);
    }
  }
}

// ---------------- attn partial reduce: (P0 + P1) * U -> bf16 ----------------
__global__ __launch_bounds__(256) void attn_reduce(
    const ushort* __restrict__ Po0, const ushort* __restrict__ Po1,
    const ushort* __restrict__ U, ushort* __restrict__ Aout){
  int i = (blockIdx.x * 256 + threadIdx.x) * 4;   // 4M elems total
  ushort4 p0 = *(const ushort4*)(Po0 + i);
  ushort4 p1 = *(const ushort4*)(Po1 + i);
  float v0 = bf2f(p0.x) + bf2f(p1.x);
  float v1 = bf2f(p0.y) + bf2f(p1.y);
  float v2 = bf2f(p0.z) + bf2f(p1.z);
  float v3 = bf2f(p0.w) + bf2f(p1.w);
  ushort4 u = *(const ushort4*)(U + i);
  ushort4 o;
  o.x = f2bf(v0 * bf2f(u.x)); o.y = f2bf(v1 * bf2f(u.y));
  o.z = f2bf(v2 * bf2f(u.z)); o.w = f2bf(v3 * bf2f(u.w));
  *(ushort4*)(Aout + i) = o;
}

// ---------------- launcher --------------------------------------------------
extern "C" void kernel_launch(void* const* d_in, const int* in_sizes, int n_in,
                              void* d_out, int out_size, void* d_ws, size_t ws_size,
                              hipStream_t stream){
  const float* seqs = (const float*)d_in[0];
  const float* bq = (const float*)d_in[3];
  const float* bk = (const float*)d_in[5];
  const float* bu = (const float*)d_in[7];
  const float* bv = (const float*)d_in[9];
  const float* bo = (const float*)d_in[11];
  const float* b1 = (const float*)d_in[13];
  const float* b2 = (const float*)d_in[15];
  const float* ln1g = (const float*)d_in[16];
  const float* ln1b = (const float*)d_in[17];
  const float* ln2g = (const float*)d_in[18];
  const float* ln2b = (const float*)d_in[19];
  const float* lnfg = (const float*)d_in[20];
  const float* lnfb = (const float*)d_in[21];

  char* base = (char*)d_ws;
  const size_t MB = 1u << 20;
  if (ws_size < 78 * MB) return;  // defensive
  ushort* wbf = (ushort*)base;                   // 14 MB
  ushort* h   = (ushort*)(base + 14 * MB);       // 8 MB (ln out; attn Po0; attn out)
  ushort* Qb  = (ushort*)(base + 22 * MB);       // 8 MB (also MLP hidden)
  ushort* Kb  = (ushort*)(base + 30 * MB);       // 8 MB
  ushort* Ub  = (ushort*)(base + 38 * MB);       // 8 MB
  ushort* Vb  = (ushort*)(base + 46 * MB);       // 8 MB (attn Po1 after transpose)
  ushort* Vt  = (ushort*)(base + 54 * MB);       // 8 MB
  float*  xb  = (float*)(base + 62 * MB);        // 16 MB
  ushort* ab  = h;

  const size_t DD = 1048576;
  for (int i = 0; i < 2; i++){
    WP wp;
    for (int j = 0; j < 7; j++)
      wp.s[j] = (const float*)d_in[2 + 2 * j] + (size_t)i * DD;
    convert_weights<<<7 * 128, 256, 0, stream>>>(wp, wbf);
    const ushort* Wl = wbf;
    const float* xin = (i == 0) ? seqs : xb;
    ln_kernel<0><<<4096, 256, 0, stream>>>(xin, ln1g + i * D_, ln1b + i * D_, nullptr, h);
    // fused QKUV projection (N=4096) with fused RoPE on Q,K
    P4 io_qkuv = {{Qb, Kb, Ub, Vb}, {bq + i * D_, bk + i * D_, bu + i * D_, bv + i * D_}};
    gemm_qkuv<<<256, 512, 0, stream>>>(h, Wl, io_qkuv);
    transpose_v<<<1024, 256, 0, stream>>>(Vb, Vt);
    attn_kernel<<<512, 256, 0, stream>>>(Qb, Kb, Vt, ab, Vb);
    attn_reduce<<<4096, 256, 0, stream>>>(ab, Vb, Ub, ab);
    gemm_k2<1><<<512, 256, 0, stream>>>(ab, Wl + 4 * DD, bo + i * D_, nullptr, xin, xb);
    ln_kernel<0><<<4096, 256, 0, stream>>>(xb, ln2g + i * D_, ln2b + i * D_, nullptr, h);
    gemm_k2<2><<<512, 256, 0, stream>>>(h, Wl + 5 * DD, b1 + i * D_, Qb, nullptr, nullptr);
    gemm_k2<1><<<512, 256, 0, stream>>>(Qb, Wl + 6 * DD, b2 + i * D_, nullptr, xb, xb);
  }
  ln_kernel<1><<<4096, 256, 0, stream>>>(xb, lnfg, lnfb, (float*)d_out, nullptr);
}

// Round 4
// 477.601 us; speedup vs baseline: 1.0598x; 1.0201x over previous
//
#include <hip/hip_runtime.h>
#include <stdint.h>

typedef __attribute__((ext_vector_type(4))) float f32x4;
typedef __attribute__((ext_vector_type(16))) float f32x16;
typedef __attribute__((ext_vector_type(8))) short s16x8;
typedef __attribute__((ext_vector_type(4))) unsigned int u32x4;

#define D_ 1024
#define LQ 2048
#define HH_ 8
#define HD_ 128

static __device__ __forceinline__ float bf2f(ushort u){
  union { unsigned int i; float f; } v; v.i = ((unsigned int)u) << 16; return v.f;
}
static __device__ __forceinline__ ushort f2bf(float f){
  union { float f; unsigned int i; } v; v.f = f;
  unsigned int r = v.i + 0x7fffu + ((v.i >> 16) & 1u);
  return (ushort)(r >> 16);
}
static __device__ __forceinline__ unsigned int pkbf(float lo, float hi){
  unsigned int r;
  asm("v_cvt_pk_bf16_f32 %0, %1, %2" : "=v"(r) : "v"(lo), "v"(hi));
  return r;
}

// ---------------- weight fp32 -> bf16 conversion (7 matrices of 1M) --------
struct WP { const float* s[7]; };
__global__ __launch_bounds__(256) void convert_weights(WP wp, ushort* __restrict__ dst){
  int w = blockIdx.x >> 7, blk = blockIdx.x & 127, t = threadIdx.x;
  const float4* s = (const float4*)wp.s[w];
  ushort4* d = (ushort4*)(dst + (size_t)w * 1048576);
  int base = blk * 2048 + t;
  #pragma unroll
  for (int r = 0; r < 8; r++){
    float4 v = s[base + r * 256];
    ushort4 o; o.x = f2bf(v.x); o.y = f2bf(v.y); o.z = f2bf(v.z); o.w = f2bf(v.w);
    d[base + r * 256] = o;
  }
}

// ---------------- layernorm: fp32 in -> bf16 (or fp32) out ------------------
template<int OUTF>
__global__ __launch_bounds__(256) void ln_kernel(const float* __restrict__ x,
    const float* __restrict__ g, const float* __restrict__ bb,
    float* __restrict__ outf, ushort* __restrict__ outb){
  int row = blockIdx.x, t = threadIdx.x;
  const float4* xr = (const float4*)(x + (size_t)row * D_);
  float4 v = xr[t];
  float s = v.x + v.y + v.z + v.w;
  float sq = v.x*v.x + v.y*v.y + v.z*v.z + v.w*v.w;
  #pragma unroll
  for (int o = 32; o; o >>= 1){ s += __shfl_down(s, o, 64); sq += __shfl_down(sq, o, 64); }
  __shared__ float red[8];
  int lane = t & 63, wv = t >> 6;
  if (!lane){ red[wv] = s; red[wv + 4] = sq; }
  __syncthreads();
  float S = red[0] + red[1] + red[2] + red[3];
  float SQ = red[4] + red[5] + red[6] + red[7];
  float m = S * (1.f / 1024.f);
  float var = SQ * (1.f / 1024.f) - m * m;
  float inv = rsqrtf(var + 1e-8f);
  float4 gv = ((const float4*)g)[t], bv = ((const float4*)bb)[t];
  float4 y;
  y.x = (v.x - m) * inv * gv.x + bv.x;
  y.y = (v.y - m) * inv * gv.y + bv.y;
  y.z = (v.z - m) * inv * gv.z + bv.z;
  y.w = (v.w - m) * inv * gv.w + bv.w;
  if (OUTF){
    ((float4*)outf)[(size_t)row * 256 + t] = y;
  } else {
    ushort4 o4; o4.x = f2bf(y.x); o4.y = f2bf(y.y); o4.z = f2bf(y.z); o4.w = f2bf(y.w);
    ((ushort4*)outb)[(size_t)row * 256 + t] = o4;
  }
}

// ---------------- GEMM 128x128, BK=64, swizzled LDS -------------------------
// LDS slot (row, j) holds global k-chunk (j ^ (row&7)); fragment reads slot
// ((kd*4+quad) ^ (row&7)) -> conflict-free.
// __launch_bounds__(256,3): 3 blocks/CU (LDS 32KB*3=96KB; 124 regs/wave*12
// waves fits) -> more cross-block overlap of the barrier vmcnt-drain (m114
// mechanism); m97's 874-912 TF point ran ~3 blocks/CU.
// EPI: 3 = QKUV fused (N=4096, dst/bias by n0>>10; RoPE on Q,K) -> bf16
struct P4 { ushort* d[4]; const float* b[4]; };

template<int EPI, int NB>
__global__ __launch_bounds__(256, 3) void gemm_k(
    const ushort* __restrict__ A, const ushort* __restrict__ W,
    P4 io, const float* __restrict__ resid, float* __restrict__ outf){
  __shared__ ushort As[128 * 64];
  __shared__ ushort Bs[128 * 64];
  int m0 = (blockIdx.x / NB) << 7;
  int n0 = (blockIdx.x % NB) << 7;
  int t = threadIdx.x, lane = t & 63, wv = t >> 6;
  int l15 = lane & 15, quad = lane >> 4;
  int wm = (wv & 1) << 6, wn = (wv >> 1) << 6;
  f32x4 acc[4][4] = {};
  for (int k0 = 0; k0 < 1024; k0 += 64){
    #pragma unroll
    for (int r = 0; r < 4; r++){
      int cb = r * 256 + wv * 64;      // wave-uniform chunk base
      int c = cb + lane;               // chunk id 0..1023
      int row = c >> 3, j = c & 7;
      int kk = ((j ^ (row & 7)) << 3); // swizzled global k-chunk
      __builtin_amdgcn_global_load_lds(
          (const __attribute__((address_space(1))) unsigned int*)(A + (size_t)(m0 + row) * 1024 + k0 + kk),
          (__attribute__((address_space(3))) unsigned int*)&As[cb * 8], 16, 0, 0);
      __builtin_amdgcn_global_load_lds(
          (const __attribute__((address_space(1))) unsigned int*)(W + (size_t)(n0 + row) * 1024 + k0 + kk),
          (__attribute__((address_space(3))) unsigned int*)&Bs[cb * 8], 16, 0, 0);
    }
    __syncthreads();
    #pragma unroll
    for (int kd = 0; kd < 2; kd++){
      s16x8 afr[4], bfr[4];
      #pragma unroll
      for (int mi = 0; mi < 4; mi++){
        int R = wm + mi * 16 + l15;
        afr[mi] = *(const s16x8*)&As[R * 64 + (((kd << 2) | quad) ^ (R & 7)) * 8];
      }
      #pragma unroll
      for (int ni = 0; ni < 4; ni++){
        int R = wn + ni * 16 + l15;
        bfr[ni] = *(const s16x8*)&Bs[R * 64 + (((kd << 2) | quad) ^ (R & 7)) * 8];
      }
      #pragma unroll
      for (int mi = 0; mi < 4; mi++)
        #pragma unroll
        for (int ni = 0; ni < 4; ni++)
          acc[mi][ni] = __builtin_amdgcn_mfma_f32_16x16x32_bf16(afr[mi], bfr[ni], acc[mi][ni], 0, 0, 0);
    }
    __syncthreads();
  }
  int sel = (EPI == 3) ? (n0 >> 10) : 0;
  ushort* dst = io.d[sel];
  const float* bias = io.b[sel];
  int ncol = (EPI == 3) ? (n0 & 1023) : n0;
  #pragma unroll
  for (int mi = 0; mi < 4; mi++){
    int gm = m0 + wm + mi * 16 + quad * 4;
    #pragma unroll
    for (int ni = 0; ni < 4; ni++){
      int cn = ncol + wn + ni * 16 + l15;
      float bv = bias[cn];
      if (EPI == 3 && sel < 2){
        // fused RoPE: pair (even,odd) cols live in lanes lane^1
        int i2 = (cn & 127) >> 1;
        float freq = __builtin_amdgcn_exp2f(-0.20762050f * (float)i2);  // 10000^(-2i/128)
        int odd = cn & 1;
        #pragma unroll
        for (int r = 0; r < 4; r++){
          float val = acc[mi][ni][r] + bv;
          float pv = __shfl_xor(val, 1, 64);
          int pos = (gm + r) & 2047;
          float ang = (float)pos * freq;
          float sv, cv; __sincosf(ang, &sv, &cv);
          float res = odd ? (pv * sv + val * cv) : (val * cv - pv * sv);
          dst[(size_t)(gm + r) * 1024 + cn] = f2bf(res);
        }
      } else {
        #pragma unroll
        for (int r = 0; r < 4; r++){
          float val = acc[mi][ni][r] + bv;
          size_t o = (size_t)(gm + r) * 1024 + cn;
          if (EPI == 1){ outf[o] = resid[o] + val; }
          else if (EPI == 2){
            float sg = __builtin_amdgcn_rcpf(1.f + __expf(-val));
            dst[o] = f2bf(val * val * sg);
          }
          else { dst[o] = f2bf(val); }
        }
      }
    }
  }
}

// ---------------- GEMM 64x128 tile, BK=64, swizzled (512 blocks) ------------
// EPI: 1 = bias + residual -> fp32 ; 2 = bias + p*silu(p) -> bf16
template<int EPI>
__global__ __launch_bounds__(256, 2) void gemm_k2(
    const ushort* __restrict__ A, const ushort* __restrict__ W,
    const float* __restrict__ bias, ushort* __restrict__ dst,
    const float* __restrict__ resid, float* __restrict__ outf){
  __shared__ ushort As[64 * 64];
  __shared__ ushort Bs[128 * 64];
  int m0 = (blockIdx.x >> 3) << 6;
  int n0 = (blockIdx.x & 7) << 7;
  int t = threadIdx.x, lane = t & 63, wv = t >> 6;
  int l15 = lane & 15, quad = lane >> 4;
  int wm = (wv & 1) << 5, wn = (wv >> 1) << 6;
  f32x4 acc[2][4] = {};
  for (int k0 = 0; k0 < 1024; k0 += 64){
    #pragma unroll
    for (int r = 0; r < 6; r++){
      int cb = (r < 2 ? r * 256 : (r - 2) * 256) + wv * 64;
      int c = cb + lane;
      int row = c >> 3, j = c & 7;
      int kk = ((j ^ (row & 7)) << 3);
      if (r < 2){
        __builtin_amdgcn_global_load_lds(
            (const __attribute__((address_space(1))) unsigned int*)(A + (size_t)(m0 + row) * 1024 + k0 + kk),
            (__attribute__((address_space(3))) unsigned int*)&As[cb * 8], 16, 0, 0);
      } else {
        __builtin_amdgcn_global_load_lds(
            (const __attribute__((address_space(1))) unsigned int*)(W + (size_t)(n0 + row) * 1024 + k0 + kk),
            (__attribute__((address_space(3))) unsigned int*)&Bs[cb * 8], 16, 0, 0);
      }
    }
    __syncthreads();
    #pragma unroll
    for (int kd = 0; kd < 2; kd++){
      s16x8 afr[2], bfr[4];
      #pragma unroll
      for (int mi = 0; mi < 2; mi++){
        int R = wm + mi * 16 + l15;
        afr[mi] = *(const s16x8*)&As[R * 64 + (((kd << 2) | quad) ^ (R & 7)) * 8];
      }
      #pragma unroll
      for (int ni = 0; ni < 4; ni++){
        int R = wn + ni * 16 + l15;
        bfr[ni] = *(const s16x8*)&Bs[R * 64 + (((kd << 2) | quad) ^ (R & 7)) * 8];
      }
      #pragma unroll
      for (int mi = 0; mi < 2; mi++)
        #pragma unroll
        for (int ni = 0; ni < 4; ni++)
          acc[mi][ni] = __builtin_amdgcn_mfma_f32_16x16x32_bf16(afr[mi], bfr[ni], acc[mi][ni], 0, 0, 0);
    }
    __syncthreads();
  }
  #pragma unroll
  for (int mi = 0; mi < 2; mi++){
    int gm = m0 + wm + mi * 16 + quad * 4;
    #pragma unroll
    for (int ni = 0; ni < 4; ni++){
      int cn = n0 + wn + ni * 16 + l15;
      float bv = bias[cn];
      #pragma unroll
      for (int r = 0; r < 4; r++){
        float val = acc[mi][ni][r] + bv;
        size_t o = (size_t)(gm + r) * 1024 + cn;
        if (EPI == 1){ outf[o] = resid[o] + val; }
        else {
          float sg = __builtin_amdgcn_rcpf(1.f + __expf(-val));
          dst[o] = f2bf(val * val * sg);
        }
      }
    }
  }
}

// ---------------- V (B,L,H,HD) -> Vt (B,H,HD,sigma(L)) ----------------------
// sigma permutes keys within each 16-block (swap bits 2<->3) so that the PV
// A-fragment's natural per-lane key order (pi) matches V's column order.
__global__ __launch_bounds__(256) void transpose_v(const ushort* __restrict__ Vb, ushort* __restrict__ Vt){
  int bidx = blockIdx.x;                 // 16 bh * 32 lt * 2 dt
  int dt = bidx & 1, lt = (bidx >> 1) & 31, bh = bidx >> 6;
  int b = bh >> 3, hh = bh & 7;
  int l0 = lt << 6, d0 = dt << 6;
  __shared__ ushort tile[64][66];
  int t = threadIdx.x;
  #pragma unroll
  for (int r = 0; r < 8; r++){
    int idx = r * 256 + t;
    int row = idx >> 5, cu = idx & 31;
    unsigned int val = *(const unsigned int*)(Vb + (size_t)(b * LQ + l0 + row) * D_ + hh * HD_ + d0 + cu * 2);
    *(unsigned int*)&tile[row][cu * 2] = val;
  }
  __syncthreads();
  #pragma unroll
  for (int r = 0; r < 8; r++){
    int idx = r * 256 + t;
    int drow = idx >> 5, lu = idx & 31;
    unsigned int val = (unsigned int)tile[lu * 2][drow] | ((unsigned int)tile[lu * 2 + 1][drow] << 16);
    int kk = lu * 2;
    int x = kk & 15;
    int kkp = (kk & 48) | ((x & 4) << 1) | ((x & 8) >> 1) | (x & 3);
    *(unsigned int*)(Vt + ((size_t)(bh * HD_ + d0 + drow)) * LQ + l0 + kkp) = val;
  }
}

// ---------------- causal silu-attention, split-K, 32x32 MFMA ----------------
// 128-q blocks, 64-key tiles, 4 waves x 32 q-rows each. Swapped QK^T
// (mfma(K,Q) -> S^T, col=q=lane&31) makes P rows lane-local; P is packed
// in-register (v_cvt_pk_bf16_f32) and used directly as the PV A-fragment:
// the kappa->key permutation is absorbed into Vt's sigma column order, so
// there is NO cross-lane exchange and NO P LDS round-trip.
__global__ __launch_bounds__(256, 2) void attn_kernel(
    const ushort* __restrict__ Q, const ushort* __restrict__ K,
    const ushort* __restrict__ Vt,
    ushort* __restrict__ Po0, ushort* __restrict__ Po1){
  __shared__ ushort Ks[2][64 * 128];
  __shared__ ushort Vs[2][128 * 64];
  int t = threadIdx.x, lane = t & 63, wv = t >> 6;
  int l31 = lane & 31, h = lane >> 5;
  int idx = blockIdx.x;
  int bh = idx & 15;
  int s = idx >> 4;
  int qt = (s < 16) ? (15 - (s >> 1)) : ((s - 16) >> 1);
  int half = s & 1;
  int ntiles = 2 * qt + 2;
  int c0 = qt + 1;
  int klo = half ? c0 : 0;
  int khi = half ? ntiles : c0;
  if (klo >= khi) return;
  int b = bh >> 3, hh = bh & 7;
  int q0 = qt << 7;
  const float scale = 0.08838834764831845f;  // 1/sqrt(128)

  // Q fragments (B-operand): col = q = lane&31, k(hd) = 16*kd + 8*h + j
  s16x8 qf[8];
  const ushort* qbase = Q + (size_t)(b * LQ + q0 + (wv << 5) + l31) * D_ + hh * HD_;
  #pragma unroll
  for (int kd = 0; kd < 8; kd++) qf[kd] = *(const s16x8*)(qbase + kd * 16 + h * 8);

  auto STAGE = [&](int p, int kt){
    int k0 = kt << 6;
    #pragma unroll
    for (int r = 0; r < 4; r++){
      int cb = r * 256 + (wv << 6);    // wave-uniform slot base
      int c = cb + lane;               // 16B slot id 0..1023
      int R = c >> 4, sl = c & 15;
      int gg = sl ^ (R & 7);           // swizzled source granule
      __builtin_amdgcn_global_load_lds(
          (const __attribute__((address_space(1))) unsigned int*)(K + (size_t)(b * LQ + k0 + R) * D_ + hh * HD_ + gg * 8),
          (__attribute__((address_space(3))) unsigned int*)&Ks[p][cb * 8], 16, 0, 0);
    }
    #pragma unroll
    for (int r = 0; r < 4; r++){
      int cb = r * 256 + (wv << 6);
      int c = cb + lane;
      int R = c >> 3, sl = c & 7;
      int gg = sl ^ (R & 7);
      __builtin_amdgcn_global_load_lds(
          (const __attribute__((address_space(1))) unsigned int*)(Vt + (size_t)(bh * HD_ + R) * LQ + k0 + gg * 8),
          (__attribute__((address_space(3))) unsigned int*)&Vs[p][cb * 8], 16, 0, 0);
    }
  };

  f32x16 acc_o[4] = {};
  int qg = q0 + (wv << 5) + l31;

  STAGE(0, klo);
  __syncthreads();
  for (int kt = klo; kt < khi; kt++){
    int p = (kt - klo) & 1;
    if (kt + 1 < khi) STAGE(p ^ 1, kt + 1);
    // swapped QK^T: S^T[key][q], col = q = lane&31
    f32x16 sacc[2] = {};
    #pragma unroll
    for (int kd = 0; kd < 8; kd++){
      #pragma unroll
      for (int kb = 0; kb < 2; kb++){
        int R = (kb << 5) + l31;
        s16x8 af = *(const s16x8*)&Ks[p][(R * 16 + (((kd << 1) | h) ^ (R & 7))) * 8];
        sacc[kb] = __builtin_amdgcn_mfma_f32_32x32x16_bf16(af, qf[kd], sacc[kb], 0, 0, 0);
      }
    }
    // silu + causal mask + in-register pack to PV A-fragments
    int k0 = kt << 6;
    s16x8 pf[4];
    #pragma unroll
    for (int kb = 0; kb < 2; kb++){
      float pvv[16];
      #pragma unroll
      for (int r = 0; r < 16; r++){
        int kg = k0 + (kb << 5) + (r & 3) + ((r >> 2) << 3) + (h << 2);
        float sv = sacc[kb][r] * scale;
        float pp = sv * __builtin_amdgcn_rcpf(1.f + __expf(-sv));
        pvv[r] = (kg <= qg) ? pp : 0.f;
      }
      #pragma unroll
      for (int cc = 0; cc < 2; cc++){
        union { u32x4 u; s16x8 v; } w;
        w.u[0] = pkbf(pvv[cc*8+0], pvv[cc*8+1]);
        w.u[1] = pkbf(pvv[cc*8+2], pvv[cc*8+3]);
        w.u[2] = pkbf(pvv[cc*8+4], pvv[cc*8+5]);
        w.u[3] = pkbf(pvv[cc*8+6], pvv[cc*8+7]);
        pf[(kb << 1) | cc] = w.v;
      }
    }
    // PV: O[q][d] += P * V  (V columns sigma-permuted to match pf key order)
    #pragma unroll
    for (int kv = 0; kv < 4; kv++){
      #pragma unroll
      for (int nt = 0; nt < 4; nt++){
        int R = (nt << 5) + l31;
        s16x8 vf = *(const s16x8*)&Vs[p][(R * 8 + (((kv << 1) | h) ^ (R & 7))) * 8];
        acc_o[nt] = __builtin_amdgcn_mfma_f32_32x32x16_bf16(pf[kv], vf, acc_o[nt], 0, 0, 0);
      }
    }
    __syncthreads();
  }
  ushort* Po = half ? Po1 : Po0;
  #pragma unroll
  for (int nt = 0; nt < 4; nt++){
    #pragma unroll
    for (int r = 0; r < 16; r++){
      int qq = q0 + (wv << 5) + (r & 3) + ((r >> 2) << 3) + (h << 2);
      int dd = (nt << 5) + l31;
      Po[(size_t)(b * LQ + qq) * D_ + hh * HD_ + dd] = f2bf(acc_o[nt][r]);
    }
  }
}

// ---------------- attn partial reduce: (P0 + P1) * U -> bf16 ----------------
__global__ __launch_bounds__(256) void attn_reduce(
    const ushort* __restrict__ Po0, const ushort* __restrict__ Po1,
    const ushort* __restrict__ U, ushort* __restrict__ Aout){
  int i = (blockIdx.x * 256 + threadIdx.x) * 4;   // 4M elems total
  ushort4 p0 = *(const ushort4*)(Po0 + i);
  ushort4 p1 = *(const ushort4*)(Po1 + i);
  float v0 = bf2f(p0.x) + bf2f(p1.x);
  float v1 = bf2f(p0.y) + bf2f(p1.y);
  float v2 = bf2f(p0.z) + bf2f(p1.z);
  float v3 = bf2f(p0.w) + bf2f(p1.w);
  ushort4 u = *(const ushort4*)(U + i);
  ushort4 o;
  o.x = f2bf(v0 * bf2f(u.x)); o.y = f2bf(v1 * bf2f(u.y));
  o.z = f2bf(v2 * bf2f(u.z)); o.w = f2bf(v3 * bf2f(u.w));
  *(ushort4*)(Aout + i) = o;
}

// ---------------- launcher --------------------------------------------------
extern "C" void kernel_launch(void* const* d_in, const int* in_sizes, int n_in,
                              void* d_out, int out_size, void* d_ws, size_t ws_size,
                              hipStream_t stream){
  const float* seqs = (const float*)d_in[0];
  const float* bq = (const float*)d_in[3];
  const float* bk = (const float*)d_in[5];
  const float* bu = (const float*)d_in[7];
  const float* bv = (const float*)d_in[9];
  const float* bo = (const float*)d_in[11];
  const float* b1 = (const float*)d_in[13];
  const float* b2 = (const float*)d_in[15];
  const float* ln1g = (const float*)d_in[16];
  const float* ln1b = (const float*)d_in[17];
  const float* ln2g = (const float*)d_in[18];
  const float* ln2b = (const float*)d_in[19];
  const float* lnfg = (const float*)d_in[20];
  const float* lnfb = (const float*)d_in[21];

  char* base = (char*)d_ws;
  const size_t MB = 1u << 20;
  if (ws_size < 78 * MB) return;  // defensive
  ushort* wbf = (ushort*)base;                   // 14 MB
  ushort* h   = (ushort*)(base + 14 * MB);       // 8 MB (ln out; attn Po0; attn out)
  ushort* Qb  = (ushort*)(base + 22 * MB);       // 8 MB (also MLP hidden)
  ushort* Kb  = (ushort*)(base + 30 * MB);       // 8 MB
  ushort* Ub  = (ushort*)(base + 38 * MB);       // 8 MB
  ushort* Vb  = (ushort*)(base + 46 * MB);       // 8 MB (attn Po1 after transpose)
  ushort* Vt  = (ushort*)(base + 54 * MB);       // 8 MB
  float*  xb  = (float*)(base + 62 * MB);        // 16 MB
  ushort* ab  = h;

  const size_t DD = 1048576;
  for (int i = 0; i < 2; i++){
    WP wp;
    for (int j = 0; j < 7; j++)
      wp.s[j] = (const float*)d_in[2 + 2 * j] + (size_t)i * DD;
    convert_weights<<<7 * 128, 256, 0, stream>>>(wp, wbf);
    const ushort* Wl = wbf;
    const float* xin = (i == 0) ? seqs : xb;
    ln_kernel<0><<<4096, 256, 0, stream>>>(xin, ln1g + i * D_, ln1b + i * D_, nullptr, h);
    // fused QKUV projection (N=4096) with fused RoPE on Q,K
    P4 io_qkuv = {{Qb, Kb, Ub, Vb}, {bq + i * D_, bk + i * D_, bu + i * D_, bv + i * D_}};
    gemm_k<3, 32><<<1024, 256, 0, stream>>>(h, Wl, io_qkuv, nullptr, nullptr);
    transpose_v<<<1024, 256, 0, stream>>>(Vb, Vt);
    attn_kernel<<<512, 256, 0, stream>>>(Qb, Kb, Vt, ab, Vb);
    attn_reduce<<<4096, 256, 0, stream>>>(ab, Vb, Ub, ab);
    gemm_k2<1><<<512, 256, 0, stream>>>(ab, Wl + 4 * DD, bo + i * D_, nullptr, xin, xb);
    ln_kernel<0><<<4096, 256, 0, stream>>>(xb, ln2g + i * D_, ln2b + i * D_, nullptr, h);
    gemm_k2<2><<<512, 256, 0, stream>>>(h, Wl + 5 * DD, b1 + i * D_, Qb, nullptr, nullptr);
    gemm_k2<1><<<512, 256, 0, stream>>>(Qb, Wl + 6 * DD, b2 + i * D_, nullptr, xb, xb);
  }
  ln_kernel<1><<<4096, 256, 0, stream>>>(xb, lnfg, lnfb, (float*)d_out, nullptr);
}